// Round 5
// baseline (174.698 us; speedup 1.0000x reference)
//
#include <hip/hip_runtime.h>
#include <hip/hip_bf16.h>
#include <stdint.h>

// B=4, L=4096, D=1024, M_MAX=512
// out[b,l,e] = smoothed[b, pbi[b,l], e] + sum_d enc[b,l,d] * W[e,d]

#define B_  4
#define L_  4096
#define D_  1024
#define M_  512

typedef __attribute__((ext_vector_type(8))) short bf16x8;
typedef __attribute__((ext_vector_type(4))) float f32x4;
typedef __attribute__((ext_vector_type(8))) unsigned short u16x8;

__device__ inline unsigned short f2bf(float f) {
    unsigned u = __float_as_uint(f);
    u += 0x7fffu + ((u >> 16) & 1u);   // RNE
    return (unsigned short)(u >> 16);
}

// ============ prep_all: enc cvt + W cvt + pbi + EMA in ONE launch (R4, unchanged) ============
__global__ void prep_all_kernel(const float* __restrict__ enc, const float* __restrict__ W,
                                const float* __restrict__ probs, const float* __restrict__ ct,
                                const int* __restrict__ bidx,
                                unsigned short* __restrict__ encb, unsigned short* __restrict__ Wb,
                                int* __restrict__ pbi, float* __restrict__ smoothed,
                                int encBlocks) {
    __shared__ int part[512];
    __shared__ float ad[M_], bdp[M_];
    __shared__ float Ac[8][64], Bc[8][64], Hin[8][64];

    const int blk = blockIdx.x;
    const int t   = threadIdx.x;

    if (blk < encBlocks + 256) {
        const float* src; unsigned short* dst; size_t i;
        if (blk < encBlocks) { src = enc; dst = encb; i = (size_t)blk * 512 + t; }
        else                 { src = W;   dst = Wb;   i = (size_t)(blk - encBlocks) * 512 + t; }
        float4 x0 = ((const float4*)src)[2 * i];
        float4 x1 = ((const float4*)src)[2 * i + 1];
        u16x8 v;
        v[0] = f2bf(x0.x); v[1] = f2bf(x0.y); v[2] = f2bf(x0.z); v[3] = f2bf(x0.w);
        v[4] = f2bf(x1.x); v[5] = f2bf(x1.y); v[6] = f2bf(x1.z); v[7] = f2bf(x1.w);
        ((u16x8*)dst)[i] = v;
    } else if (blk < encBlocks + 260) {
        int b = blk - (encBlocks + 256);
        const float4* pr = (const float4*)(probs + b * L_);
        int cnt[8]; int s = 0;
        #pragma unroll
        for (int u = 0; u < 2; ++u) {
            float4 x = pr[t * 2 + u];
            s += (x.x >= 0.5f); cnt[u * 4 + 0] = s;
            s += (x.y >= 0.5f); cnt[u * 4 + 1] = s;
            s += (x.z >= 0.5f); cnt[u * 4 + 2] = s;
            s += (x.w >= 0.5f); cnt[u * 4 + 3] = s;
        }
        part[t] = s;
        __syncthreads();
        for (int off = 1; off < 512; off <<= 1) {
            int x = part[t];
            int y = (t >= off) ? part[t - off] : 0;
            __syncthreads();
            part[t] = x + y;
            __syncthreads();
        }
        int excl = part[t] - s;
        int4* po = (int4*)(pbi + b * L_ + t * 8);
        #pragma unroll
        for (int u = 0; u < 2; ++u) {
            int4 o;
            o.x = max(excl + cnt[u * 4 + 0] - 1, 0);
            o.y = max(excl + cnt[u * 4 + 1] - 1, 0);
            o.z = max(excl + cnt[u * 4 + 2] - 1, 0);
            o.w = max(excl + cnt[u * 4 + 3] - 1, 0);
            po[u] = o;
        }
    } else {
        int idx = blk - (encBlocks + 260);
        int b  = idx >> 4;
        int d0 = (idx & 15) * 64;
        int dl = t & 63;
        int ch = t >> 6;
        {
            int m = t;
            int bi = bidx[b * M_ + m];
            float p = fmaxf(probs[b * L_ + bi], 0.1f);
            ad[m]  = (m == 0) ? 0.0f : fmaxf(1.0f - p, 1e-7f);
            bdp[m] = (m == 0) ? 1.0f : p;
        }
        __syncthreads();
        const float* ctp = ct + ((size_t)b * M_ + ch * 64) * D_ + d0 + dl;
        float A = 1.0f, Bv = 0.0f;
        #pragma unroll 8
        for (int i = 0; i < 64; ++i) {
            int m = ch * 64 + i;
            float c = ctp[(size_t)i * D_];
            A  = ad[m] * A;
            Bv = ad[m] * Bv + bdp[m] * c;
        }
        Ac[ch][dl] = A; Bc[ch][dl] = Bv;
        __syncthreads();
        if (t < 64) {
            float H = 0.0f;
            #pragma unroll
            for (int c = 0; c < 8; ++c) {
                Hin[c][t] = H;
                H = Ac[c][t] * H + Bc[c][t];
            }
        }
        __syncthreads();
        float h = Hin[ch][dl];
        float* smp = smoothed + ((size_t)b * M_ + ch * 64) * D_ + d0 + dl;
        #pragma unroll 8
        for (int i = 0; i < 64; ++i) {
            int m = ch * 64 + i;
            float c = ctp[(size_t)i * D_];
            h = ad[m] * h + bdp[m] * c;
            smp[(size_t)i * D_] = h;
        }
    }
}

// ============ GEMM: 256x128 tile, BK=32, 3-buffer counted-vmcnt, 2 blocks/CU ============
// 512 thr = 8 waves (2M x 4N); per-wave 128x32 out = 8x2 16x16 frags.
// LDS 72 KiB: 3 x (A 256x32 + B 128x32) bf16, 64-B rows, XOR swizzle col bits4-5 by row&3.
#define NT_ 32   // K tiles

__global__ __launch_bounds__(512, 4) void gemm3_kernel(
    const unsigned short* __restrict__ encb, const unsigned short* __restrict__ Wb,
    const float* __restrict__ smoothed, const int* __restrict__ pbi,
    float* __restrict__ out)
{
    __shared__ __align__(16) unsigned short As[3][256 * 32];
    __shared__ __align__(16) unsigned short Bs[3][128 * 32];

    const int tid  = threadIdx.x;
    const int lane = tid & 63;
    const int w    = tid >> 6;        // 0..7
    const int wm   = w >> 2;          // 0..1  (M half: 128 rows)
    const int wn   = w & 3;           // 0..3  (N quarter: 32 cols)
    const int l15  = lane & 15;
    const int l16  = lane >> 4;

    // bijective XCD swizzle: 512 blocks, XCD x gets rowTiles [8x, 8x+8) x all 8 colTiles
    const int orig = blockIdx.x;
    const int rm   = (orig & 7) * 64 + (orig >> 3);
    const size_t rowBase = (size_t)(rm >> 3) * 256;
    const int    colBase = (rm & 7) * 128;

    // stage pre-swizzle: LDS linear (row = w*16 + lane>>2, col8 = (lane&3)*8 elems);
    // source col elems = col8 ^ ((row&3)<<3)
    const int rsw = (((lane & 3) ^ ((lane >> 2) & 3)) << 3);

#define STAGE(kt, s)                                                                      \
  {                                                                                       \
    int row_ = w * 16 + (lane >> 2);                                                      \
    const unsigned short* ga0_ = encb + (rowBase + row_) * D_ + (kt) * 32 + rsw;          \
    __builtin_amdgcn_global_load_lds(                                                     \
        (const __attribute__((address_space(1))) void*)ga0_,                              \
        (__attribute__((address_space(3))) void*)&As[s][w * 512], 16, 0, 0);              \
    const unsigned short* ga1_ = encb + (rowBase + 128 + row_) * D_ + (kt) * 32 + rsw;    \
    __builtin_amdgcn_global_load_lds(                                                     \
        (const __attribute__((address_space(1))) void*)ga1_,                              \
        (__attribute__((address_space(3))) void*)&As[s][4096 + w * 512], 16, 0, 0);       \
    const unsigned short* gb_ = Wb + (size_t)(colBase + row_) * D_ + (kt) * 32 + rsw;     \
    __builtin_amdgcn_global_load_lds(                                                     \
        (const __attribute__((address_space(1))) void*)gb_,                               \
        (__attribute__((address_space(3))) void*)&Bs[s][w * 512], 16, 0, 0);              \
  }

    f32x4 acc[8][2] = {};

    STAGE(0, 0);
    STAGE(1, 1);
    asm volatile("s_waitcnt vmcnt(3)" ::: "memory");   // tile0's 3 loads done; barrier => all waves
    __builtin_amdgcn_s_barrier();
    __builtin_amdgcn_sched_barrier(0);

    int s = 0;
    for (int t = 0; t < NT_; ++t) {
        const char* aB = (const char*)As[s];
        const char* bB = (const char*)Bs[s];
        const int swz = (l15 & 3) << 4;
        bf16x8 a[8], bb[2];
        #pragma unroll
        for (int m = 0; m < 8; ++m)
            a[m] = *(const bf16x8*)(aB + (wm * 128 + m * 16 + l15) * 64 + ((l16 * 16) ^ swz));
        #pragma unroll
        for (int n = 0; n < 2; ++n)
            bb[n] = *(const bf16x8*)(bB + (wn * 32 + n * 16 + l15) * 64 + ((l16 * 16) ^ swz));

        int s2 = s + 2; if (s2 >= 3) s2 -= 3;
        if (t + 2 < NT_) STAGE(t + 2, s2);   // buf consumed at tile t-1; safe after boundary barrier

        __builtin_amdgcn_s_setprio(1);
        #pragma unroll
        for (int m = 0; m < 8; ++m)
            #pragma unroll
            for (int n = 0; n < 2; ++n)
                acc[m][n] = __builtin_amdgcn_mfma_f32_16x16x32_bf16(a[m], bb[n], acc[m][n], 0, 0, 0);
        __builtin_amdgcn_s_setprio(0);

        if (t + 1 < NT_) {
            if (t + 2 < NT_) { asm volatile("s_waitcnt vmcnt(3)" ::: "memory"); }
            else             { asm volatile("s_waitcnt vmcnt(0)" ::: "memory"); }
            __builtin_amdgcn_s_barrier();
            __builtin_amdgcn_sched_barrier(0);
        }
        s += 1; if (s >= 3) s -= 3;
    }
#undef STAGE

    // epilogue: fused plugback gather + add, fp32 store
    #pragma unroll
    for (int m = 0; m < 8; ++m) {
        const size_t row0 = rowBase + wm * 128 + m * 16;
        #pragma unroll
        for (int j = 0; j < 4; ++j) {
            size_t row = row0 + l16 * 4 + j;
            int b  = (int)(row >> 12);
            int pb = pbi[row];
            pb = pb < (M_ - 1) ? pb : (M_ - 1);
            const float* sm = smoothed + ((size_t)(b * M_ + pb)) * D_;
            #pragma unroll
            for (int n = 0; n < 2; ++n) {
                int col = colBase + wn * 32 + n * 16 + l15;
                out[row * D_ + col] = acc[m][n][j] + sm[col];
            }
        }
    }
}

// ---------------- fallback fused-convert GEMM (if ws too small; unlikely path) ----------------
#define LDP 72
__global__ __launch_bounds__(256, 2) void gemm_fused_kernel(
    const float* __restrict__ enc, const unsigned short* __restrict__ Wb,
    const float* __restrict__ smoothed, const int* __restrict__ pbi,
    float* __restrict__ out)
{
    __shared__ unsigned short Asf[128][LDP];
    __shared__ unsigned short Bsf[128][LDP];
    const int tid  = threadIdx.x;
    const int lane = tid & 63;
    const int wid  = tid >> 6;
    const int wm   = wid >> 1;
    const int wn   = wid & 1;
    const int l15  = lane & 15;
    const int l16  = lane >> 4;
    const size_t rowBase = (size_t)blockIdx.x * 128;
    const int    colBase = blockIdx.y * 128;
    f32x4 acc[4][4] = {};
    for (int t = 0; t < D_ / 64; ++t) {
        const int k0 = t * 64;
        #pragma unroll
        for (int i = 0; i < 4; ++i) {
            int c = i * 256 + tid;
            int r = c >> 3;
            int c8 = c & 7;
            const float4* g = (const float4*)(enc + (rowBase + r) * D_ + k0 + c8 * 8);
            float4 x0 = g[0];
            float4 x1 = g[1];
            u16x8 v;
            v[0] = f2bf(x0.x); v[1] = f2bf(x0.y); v[2] = f2bf(x0.z); v[3] = f2bf(x0.w);
            v[4] = f2bf(x1.x); v[5] = f2bf(x1.y); v[6] = f2bf(x1.z); v[7] = f2bf(x1.w);
            *(u16x8*)&Asf[r][c8 * 8] = v;
        }
        #pragma unroll
        for (int i = 0; i < 4; ++i) {
            int c = i * 256 + tid;
            int r = c >> 3;
            int c8 = c & 7;
            u16x8 v = *(const u16x8*)(Wb + (size_t)(colBase + r) * D_ + k0 + c8 * 8);
            *(u16x8*)&Bsf[r][c8 * 8] = v;
        }
        __syncthreads();
        #pragma unroll
        for (int kk = 0; kk < 2; ++kk) {
            bf16x8 a[4], bbf[4];
            #pragma unroll
            for (int m = 0; m < 4; ++m)
                a[m] = *(const bf16x8*)&Asf[wm * 64 + m * 16 + l15][kk * 32 + l16 * 8];
            #pragma unroll
            for (int n = 0; n < 4; ++n)
                bbf[n] = *(const bf16x8*)&Bsf[wn * 64 + n * 16 + l15][kk * 32 + l16 * 8];
            #pragma unroll
            for (int m = 0; m < 4; ++m)
                #pragma unroll
                for (int n = 0; n < 4; ++n)
                    acc[m][n] = __builtin_amdgcn_mfma_f32_16x16x32_bf16(a[m], bbf[n], acc[m][n], 0, 0, 0);
        }
        __syncthreads();
    }
    #pragma unroll
    for (int m = 0; m < 4; ++m) {
        #pragma unroll
        for (int j = 0; j < 4; ++j) {
            size_t row = rowBase + wm * 64 + m * 16 + l16 * 4 + j;
            int b  = (int)(row >> 12);
            int pb = pbi[row];
            pb = pb < (M_ - 1) ? pb : (M_ - 1);
            const float* sm = smoothed + ((size_t)(b * M_ + pb)) * D_;
            #pragma unroll
            for (int n = 0; n < 4; ++n) {
                int col = colBase + wn * 64 + n * 16 + l15;
                out[row * D_ + col] = acc[m][n][j] + sm[col];
            }
        }
    }
}

extern "C" void kernel_launch(void* const* d_in, const int* in_sizes, int n_in,
                              void* d_out, int out_size, void* d_ws, size_t ws_size,
                              hipStream_t stream) {
    const float* ct    = (const float*)d_in[0];
    const float* enc   = (const float*)d_in[1];
    const float* probs = (const float*)d_in[2];
    const int*   bidx  = (const int*)d_in[3];
    const float* W     = (const float*)d_in[5];
    float* out = (float*)d_out;
    char*  ws  = (char*)d_ws;

    const size_t SZ_ENCB = (size_t)B_ * L_ * D_ * 2;   // 32 MiB
    const size_t SZ_SM   = (size_t)B_ * M_ * D_ * 4;   // 8 MiB
    const size_t SZ_PBI  = (size_t)B_ * L_ * 4;        // 64 KiB
    const size_t SZ_WB   = (size_t)D_ * D_ * 2;        // 2 MiB

    if (ws_size >= SZ_ENCB + SZ_SM + SZ_PBI + SZ_WB) {
        unsigned short* encb     = (unsigned short*)ws;
        float*          smoothed = (float*)(ws + SZ_ENCB);
        int*            pbi      = (int*)(ws + SZ_ENCB + SZ_SM);
        unsigned short* Wb       = (unsigned short*)(ws + SZ_ENCB + SZ_SM + SZ_PBI);

        const int encBlocks = B_ * L_ * D_ / 4096;   // 4096
        const int nBlocks   = encBlocks + 256 + B_ + B_ * D_ / 64;  // 4420
        hipLaunchKernelGGL(prep_all_kernel, dim3(nBlocks), dim3(512), 0, stream,
                           enc, W, probs, ct, bidx, encb, Wb, pbi, smoothed, encBlocks);
        hipLaunchKernelGGL(gemm3_kernel, dim3(512), dim3(512), 0, stream,
                           encb, Wb, smoothed, pbi, out);
    } else {
        float*          smoothed = (float*)ws;
        int*            pbi      = (int*)(ws + SZ_SM);
        unsigned short* Wb       = (unsigned short*)(ws + SZ_SM + SZ_PBI);
        const int nBlocks = 0 + 256 + B_ + B_ * D_ / 64;
        hipLaunchKernelGGL(prep_all_kernel, dim3(nBlocks), dim3(512), 0, stream,
                           enc, W, probs, ct, bidx, (unsigned short*)ws /*unused*/, Wb, pbi, smoothed, 0);
        hipLaunchKernelGGL(gemm_fused_kernel, dim3(B_ * L_ / 128, D_ / 128), dim3(256), 0, stream,
                           enc, Wb, smoothed, pbi, out);
    }
}

// Round 6
// 173.231 us; speedup vs baseline: 1.0085x; 1.0085x over previous
//
#include <hip/hip_runtime.h>
#include <hip/hip_bf16.h>
#include <stdint.h>

// B=4, L=4096, D=1024, M_MAX=512
// out[b,l,e] = smoothed[b, pbi[b,l], e] + sum_d enc[b,l,d] * W[e,d]

#define B_  4
#define L_  4096
#define D_  1024
#define M_  512

typedef __attribute__((ext_vector_type(8))) short bf16x8;
typedef __attribute__((ext_vector_type(4))) float f32x4;
typedef __attribute__((ext_vector_type(8))) unsigned short u16x8;

__device__ inline unsigned short f2bf(float f) {
    unsigned u = __float_as_uint(f);
    u += 0x7fffu + ((u >> 16) & 1u);   // RNE
    return (unsigned short)(u >> 16);
}

// ============ prep_all: enc cvt + W cvt + pbi + EMA in ONE launch (unchanged control) ============
__global__ void prep_all_kernel(const float* __restrict__ enc, const float* __restrict__ W,
                                const float* __restrict__ probs, const float* __restrict__ ct,
                                const int* __restrict__ bidx,
                                unsigned short* __restrict__ encb, unsigned short* __restrict__ Wb,
                                int* __restrict__ pbi, float* __restrict__ smoothed,
                                int encBlocks) {
    __shared__ int part[512];
    __shared__ float ad[M_], bdp[M_];
    __shared__ float Ac[8][64], Bc[8][64], Hin[8][64];

    const int blk = blockIdx.x;
    const int t   = threadIdx.x;

    if (blk < encBlocks + 256) {
        const float* src; unsigned short* dst; size_t i;
        if (blk < encBlocks) { src = enc; dst = encb; i = (size_t)blk * 512 + t; }
        else                 { src = W;   dst = Wb;   i = (size_t)(blk - encBlocks) * 512 + t; }
        float4 x0 = ((const float4*)src)[2 * i];
        float4 x1 = ((const float4*)src)[2 * i + 1];
        u16x8 v;
        v[0] = f2bf(x0.x); v[1] = f2bf(x0.y); v[2] = f2bf(x0.z); v[3] = f2bf(x0.w);
        v[4] = f2bf(x1.x); v[5] = f2bf(x1.y); v[6] = f2bf(x1.z); v[7] = f2bf(x1.w);
        ((u16x8*)dst)[i] = v;
    } else if (blk < encBlocks + 260) {
        int b = blk - (encBlocks + 256);
        const float4* pr = (const float4*)(probs + b * L_);
        int cnt[8]; int s = 0;
        #pragma unroll
        for (int u = 0; u < 2; ++u) {
            float4 x = pr[t * 2 + u];
            s += (x.x >= 0.5f); cnt[u * 4 + 0] = s;
            s += (x.y >= 0.5f); cnt[u * 4 + 1] = s;
            s += (x.z >= 0.5f); cnt[u * 4 + 2] = s;
            s += (x.w >= 0.5f); cnt[u * 4 + 3] = s;
        }
        part[t] = s;
        __syncthreads();
        for (int off = 1; off < 512; off <<= 1) {
            int x = part[t];
            int y = (t >= off) ? part[t - off] : 0;
            __syncthreads();
            part[t] = x + y;
            __syncthreads();
        }
        int excl = part[t] - s;
        int4* po = (int4*)(pbi + b * L_ + t * 8);
        #pragma unroll
        for (int u = 0; u < 2; ++u) {
            int4 o;
            o.x = max(excl + cnt[u * 4 + 0] - 1, 0);
            o.y = max(excl + cnt[u * 4 + 1] - 1, 0);
            o.z = max(excl + cnt[u * 4 + 2] - 1, 0);
            o.w = max(excl + cnt[u * 4 + 3] - 1, 0);
            po[u] = o;
        }
    } else {
        int idx = blk - (encBlocks + 260);
        int b  = idx >> 4;
        int d0 = (idx & 15) * 64;
        int dl = t & 63;
        int ch = t >> 6;
        {
            int m = t;
            int bi = bidx[b * M_ + m];
            float p = fmaxf(probs[b * L_ + bi], 0.1f);
            ad[m]  = (m == 0) ? 0.0f : fmaxf(1.0f - p, 1e-7f);
            bdp[m] = (m == 0) ? 1.0f : p;
        }
        __syncthreads();
        const float* ctp = ct + ((size_t)b * M_ + ch * 64) * D_ + d0 + dl;
        float A = 1.0f, Bv = 0.0f;
        #pragma unroll 8
        for (int i = 0; i < 64; ++i) {
            int m = ch * 64 + i;
            float c = ctp[(size_t)i * D_];
            A  = ad[m] * A;
            Bv = ad[m] * Bv + bdp[m] * c;
        }
        Ac[ch][dl] = A; Bc[ch][dl] = Bv;
        __syncthreads();
        if (t < 64) {
            float H = 0.0f;
            #pragma unroll
            for (int c = 0; c < 8; ++c) {
                Hin[c][t] = H;
                H = Ac[c][t] * H + Bc[c][t];
            }
        }
        __syncthreads();
        float h = Hin[ch][dl];
        float* smp = smoothed + ((size_t)b * M_ + ch * 64) * D_ + d0 + dl;
        #pragma unroll 8
        for (int i = 0; i < 64; ++i) {
            int m = ch * 64 + i;
            float c = ctp[(size_t)i * D_];
            h = ad[m] * h + bdp[m] * c;
            smp[(size_t)i * D_] = h;
        }
    }
}

// ============ GEMM: 256x256, BK=64, m201-style 8-phase counted-vmcnt schedule ============
// 512 thr = 8 waves (2M x 4N); per-wave 128x64 out = 8x4 16x16 frags.
// LDS 128 KiB: A[db][half] 128x64 bf16 (16KiB each) at (db*2+h)*16384;
//              B[db][half] at 65536 + (db*2+h)*16384.
// st_16x32 swizzle: byte ^= ((byte>>9)&1)<<5 within each half (source pre-swizzled, rule #21).
// Schedule per iter i (tiles T=2i in db0, 2i+1 in db1), one half-tile stage (2 loads/thr) per phase:
//   ph1: rd A[0-3],B[0-1] db0 | stage A0(2i+1)->db1 | MFMA (m0-3,n0-1)
//   ph2: rd B[2-3] db0       | stage A1(2i+1)->db1 | MFMA (m0-3,n2-3)
//   ph3: rd A[4-7] db0       | stage B0(2i+2)->db0 | MFMA (m4-7,n0-1)
//   ph4:                      | stage B1(2i+2)->db0 | vmcnt(4) | MFMA (m4-7,n2-3)
//   ph5-8: mirror on db1, staging A0/A1(2i+2)->db0, B0/B1(2i+3)->db1, vmcnt(4) at ph8.
// Tile indices clamped to 15 => last-iter schedule identical, dead stages rewrite T15 (safe).
#define NTT 16   // K tiles (K=1024 / BK=64)

__global__ __launch_bounds__(512, 2) void gemm8_kernel(
    const unsigned short* __restrict__ encb, const unsigned short* __restrict__ Wb,
    const float* __restrict__ smoothed, const int* __restrict__ pbi,
    float* __restrict__ out)
{
    __shared__ __align__(16) char smem[131072];

    const int tid  = threadIdx.x;
    const int lane = tid & 63;
    const int w    = tid >> 6;        // 0..7
    const int wm   = w >> 2;          // 0..1
    const int wn   = w & 3;           // 0..3
    const int l15  = lane & 15;
    const int l16  = lane >> 4;

    // bijective XCD swizzle: 256 blocks over 8 XCDs; each XCD gets 8 row-tiles x 4 col-tiles
    const int orig = blockIdx.x;
    const int rm   = (orig & 7) * 32 + (orig >> 3);
    const size_t rowBase = (size_t)(rm >> 2) * 256;
    const int    colBase = (rm & 3) * 256;

    // ds-read swizzled column bytes (bit9 of byte-in-half = (rowInHalf>>2)&1 = (l15>>2)&1)
    const int rsw5  = ((l15 >> 2) & 1) << 5;
    const int colb0 = (0 + l16 * 16) ^ rsw5;
    const int colb1 = (64 + l16 * 16) ^ rsw5;

    // per-dbuf read bases (byte offsets into smem)
    const int aRd0 = (0 + wm) * 16384 + l15 * 128;
    const int aRd1 = (2 + wm) * 16384 + l15 * 128;
    const int bRd0 = 65536 + (0 + (wn >> 1)) * 16384 + ((wn & 1) * 64 + l15) * 128;
    const int bRd1 = 65536 + (2 + (wn >> 1)) * 16384 + ((wn & 1) * 64 + l15) * 128;

    // staging: thread handles rows {srow, 64+srow}, 16B slot sslot (source pre-swizzled)
    const int srow  = tid >> 3;                                  // 0..63
    const int sslot = (tid & 7) ^ (((tid >> 5) & 1) << 1);       // slot ^ ((srow>>2)&1)<<1
    const unsigned short* aSrc = encb + (rowBase + srow) * D_ + sslot * 8;
    const unsigned short* bSrc = Wb + ((size_t)colBase + srow) * D_ + sslot * 8;

#define STAGE_A(T, db, h)                                                                 \
  { _Pragma("unroll") for (int i_ = 0; i_ < 2; ++i_) {                                    \
      const unsigned short* g_ = aSrc + (size_t)((h) * 128 + i_ * 64) * D_ + (T) * 64;    \
      __builtin_amdgcn_global_load_lds(                                                   \
          (const __attribute__((address_space(1))) void*)g_,                              \
          (__attribute__((address_space(3))) void*)(smem + ((db)*2+(h))*16384 + i_*8192 + tid*16), \
          16, 0, 0); } }

#define STAGE_B(T, db, h)                                                                 \
  { _Pragma("unroll") for (int i_ = 0; i_ < 2; ++i_) {                                    \
      const unsigned short* g_ = bSrc + (size_t)((h) * 128 + i_ * 64) * D_ + (T) * 64;    \
      __builtin_amdgcn_global_load_lds(                                                   \
          (const __attribute__((address_space(1))) void*)g_,                              \
          (__attribute__((address_space(3))) void*)(smem + 65536 + ((db)*2+(h))*16384 + i_*8192 + tid*16), \
          16, 0, 0); } }

#define LDSA(aRd, mbase)                                                                  \
  { _Pragma("unroll") for (int m_ = 0; m_ < 4; ++m_) {                                    \
      a[m_*2+0] = *(const bf16x8*)(smem + (aRd) + ((mbase)+m_)*2048 + colb0);             \
      a[m_*2+1] = *(const bf16x8*)(smem + (aRd) + ((mbase)+m_)*2048 + colb1); } }

#define LDSB(bRd, nbase)                                                                  \
  { _Pragma("unroll") for (int n_ = 0; n_ < 2; ++n_) {                                    \
      b[((nbase)+n_)*2+0] = *(const bf16x8*)(smem + (bRd) + ((nbase)+n_)*2048 + colb0);   \
      b[((nbase)+n_)*2+1] = *(const bf16x8*)(smem + (bRd) + ((nbase)+n_)*2048 + colb1); } }

#define MFMA_Q(mbase, nbase)                                                              \
  { _Pragma("unroll") for (int m_ = 0; m_ < 4; ++m_)                                      \
    _Pragma("unroll") for (int n_ = 0; n_ < 2; ++n_) {                                    \
      acc[(mbase)+m_][(nbase)+n_] = __builtin_amdgcn_mfma_f32_16x16x32_bf16(              \
          a[m_*2+0], b[((nbase)+n_)*2+0], acc[(mbase)+m_][(nbase)+n_], 0, 0, 0);          \
      acc[(mbase)+m_][(nbase)+n_] = __builtin_amdgcn_mfma_f32_16x16x32_bf16(              \
          a[m_*2+1], b[((nbase)+n_)*2+1], acc[(mbase)+m_][(nbase)+n_], 0, 0, 0); } }

#define PH_OPEN()  do { __builtin_amdgcn_sched_barrier(0); __builtin_amdgcn_s_barrier();  \
    __builtin_amdgcn_sched_barrier(0);                                                    \
    asm volatile("s_waitcnt lgkmcnt(0)" ::: "memory");                                    \
    __builtin_amdgcn_sched_barrier(0); __builtin_amdgcn_s_setprio(1); } while (0)

#define PH_CLOSE() do { __builtin_amdgcn_s_setprio(0); __builtin_amdgcn_sched_barrier(0); \
    __builtin_amdgcn_s_barrier(); __builtin_amdgcn_sched_barrier(0); } while (0)

    f32x4 acc[8][4] = {};
    bf16x8 a[8], b[8];

    // ---- prologue: T0 full + T1 B-halves (12 loads/thr); confirm T0 (allow T1-B outstanding) ----
    STAGE_A(0, 0, 0); STAGE_A(0, 0, 1);
    STAGE_B(0, 0, 0); STAGE_B(0, 0, 1);
    STAGE_B(1, 1, 0); STAGE_B(1, 1, 1);
    asm volatile("s_waitcnt vmcnt(4)" ::: "memory");
    __builtin_amdgcn_s_barrier();
    __builtin_amdgcn_sched_barrier(0);

    #pragma unroll 1
    for (int i = 0; i < NTT / 2; ++i) {
        const int t1 = 2 * i + 1;
        const int t2 = (2 * i + 2 < NTT) ? 2 * i + 2 : NTT - 1;
        const int t3 = (2 * i + 3 < NTT) ? 2 * i + 3 : NTT - 1;
        // ph1
        LDSA(aRd0, 0); LDSB(bRd0, 0);
        STAGE_A(t1, 1, 0);
        PH_OPEN(); MFMA_Q(0, 0); PH_CLOSE();
        // ph2
        LDSB(bRd0, 2);
        STAGE_A(t1, 1, 1);
        PH_OPEN(); MFMA_Q(0, 2); PH_CLOSE();
        // ph3
        LDSA(aRd0, 4);
        STAGE_B(t2, 0, 0);
        PH_OPEN(); MFMA_Q(4, 0); PH_CLOSE();
        // ph4
        STAGE_B(t2, 0, 1);
        asm volatile("s_waitcnt vmcnt(4)" ::: "memory");
        PH_OPEN(); MFMA_Q(4, 2); PH_CLOSE();
        // ph5
        LDSA(aRd1, 0); LDSB(bRd1, 0);
        STAGE_A(t2, 0, 0);
        PH_OPEN(); MFMA_Q(0, 0); PH_CLOSE();
        // ph6
        LDSB(bRd1, 2);
        STAGE_A(t2, 0, 1);
        PH_OPEN(); MFMA_Q(0, 2); PH_CLOSE();
        // ph7
        LDSA(aRd1, 4);
        STAGE_B(t3, 1, 0);
        PH_OPEN(); MFMA_Q(4, 0); PH_CLOSE();
        // ph8
        STAGE_B(t3, 1, 1);
        asm volatile("s_waitcnt vmcnt(4)" ::: "memory");
        PH_OPEN(); MFMA_Q(4, 2); PH_CLOSE();
    }
#undef STAGE_A
#undef STAGE_B
#undef LDSA
#undef LDSB
#undef MFMA_Q
#undef PH_OPEN
#undef PH_CLOSE

    // ---- epilogue: fused plugback gather + add, fp32 store ----
    #pragma unroll
    for (int m = 0; m < 8; ++m) {
        const size_t row0 = rowBase + wm * 128 + m * 16;
        #pragma unroll
        for (int j = 0; j < 4; ++j) {
            size_t row = row0 + l16 * 4 + j;
            int bb2 = (int)(row >> 12);
            int pb  = pbi[row];
            pb = pb < (M_ - 1) ? pb : (M_ - 1);
            const float* sm = smoothed + ((size_t)(bb2 * M_ + pb)) * D_;
            #pragma unroll
            for (int n = 0; n < 4; ++n) {
                int col = colBase + wn * 64 + n * 16 + l15;
                out[row * D_ + col] = acc[m][n][j] + sm[col];
            }
        }
    }
}

// ---------------- fallback fused-convert GEMM (if ws too small; unlikely path) ----------------
#define LDP 72
__global__ __launch_bounds__(256, 2) void gemm_fused_kernel(
    const float* __restrict__ enc, const unsigned short* __restrict__ Wb,
    const float* __restrict__ smoothed, const int* __restrict__ pbi,
    float* __restrict__ out)
{
    __shared__ unsigned short Asf[128][LDP];
    __shared__ unsigned short Bsf[128][LDP];
    const int tid  = threadIdx.x;
    const int lane = tid & 63;
    const int wid  = tid >> 6;
    const int wm   = wid >> 1;
    const int wn   = wid & 1;
    const int l15  = lane & 15;
    const int l16  = lane >> 4;
    const size_t rowBase = (size_t)blockIdx.x * 128;
    const int    colBase = blockIdx.y * 128;
    f32x4 acc[4][4] = {};
    for (int t = 0; t < D_ / 64; ++t) {
        const int k0 = t * 64;
        #pragma unroll
        for (int i = 0; i < 4; ++i) {
            int c = i * 256 + tid;
            int r = c >> 3;
            int c8 = c & 7;
            const float4* g = (const float4*)(enc + (rowBase + r) * D_ + k0 + c8 * 8);
            float4 x0 = g[0];
            float4 x1 = g[1];
            u16x8 v;
            v[0] = f2bf(x0.x); v[1] = f2bf(x0.y); v[2] = f2bf(x0.z); v[3] = f2bf(x0.w);
            v[4] = f2bf(x1.x); v[5] = f2bf(x1.y); v[6] = f2bf(x1.z); v[7] = f2bf(x1.w);
            *(u16x8*)&Asf[r][c8 * 8] = v;
        }
        #pragma unroll
        for (int i = 0; i < 4; ++i) {
            int c = i * 256 + tid;
            int r = c >> 3;
            int c8 = c & 7;
            u16x8 v = *(const u16x8*)(Wb + (size_t)(colBase + r) * D_ + k0 + c8 * 8);
            *(u16x8*)&Bsf[r][c8 * 8] = v;
        }
        __syncthreads();
        #pragma unroll
        for (int kk = 0; kk < 2; ++kk) {
            bf16x8 a[4], bbf[4];
            #pragma unroll
            for (int m = 0; m < 4; ++m)
                a[m] = *(const bf16x8*)&Asf[wm * 64 + m * 16 + l15][kk * 32 + l16 * 8];
            #pragma unroll
            for (int n = 0; n < 4; ++n)
                bbf[n] = *(const bf16x8*)&Bsf[wn * 64 + n * 16 + l15][kk * 32 + l16 * 8];
            #pragma unroll
            for (int m = 0; m < 4; ++m)
                #pragma unroll
                for (int n = 0; n < 4; ++n)
                    acc[m][n] = __builtin_amdgcn_mfma_f32_16x16x32_bf16(a[m], bbf[n], acc[m][n], 0, 0, 0);
        }
        __syncthreads();
    }
    #pragma unroll
    for (int m = 0; m < 4; ++m) {
        #pragma unroll
        for (int j = 0; j < 4; ++j) {
            size_t row = rowBase + wm * 64 + m * 16 + l16 * 4 + j;
            int b  = (int)(row >> 12);
            int pb = pbi[row];
            pb = pb < (M_ - 1) ? pb : (M_ - 1);
            const float* sm = smoothed + ((size_t)(b * M_ + pb)) * D_;
            #pragma unroll
            for (int n = 0; n < 4; ++n) {
                int col = colBase + wn * 64 + n * 16 + l15;
                out[row * D_ + col] = acc[m][n][j] + sm[col];
            }
        }
    }
}

extern "C" void kernel_launch(void* const* d_in, const int* in_sizes, int n_in,
                              void* d_out, int out_size, void* d_ws, size_t ws_size,
                              hipStream_t stream) {
    const float* ct    = (const float*)d_in[0];
    const float* enc   = (const float*)d_in[1];
    const float* probs = (const float*)d_in[2];
    const int*   bidx  = (const int*)d_in[3];
    const float* W     = (const float*)d_in[5];
    float* out = (float*)d_out;
    char*  ws  = (char*)d_ws;

    const size_t SZ_ENCB = (size_t)B_ * L_ * D_ * 2;   // 32 MiB
    const size_t SZ_SM   = (size_t)B_ * M_ * D_ * 4;   // 8 MiB
    const size_t SZ_PBI  = (size_t)B_ * L_ * 4;        // 64 KiB
    const size_t SZ_WB   = (size_t)D_ * D_ * 2;        // 2 MiB

    if (ws_size >= SZ_ENCB + SZ_SM + SZ_PBI + SZ_WB) {
        unsigned short* encb     = (unsigned short*)ws;
        float*          smoothed = (float*)(ws + SZ_ENCB);
        int*            pbi      = (int*)(ws + SZ_ENCB + SZ_SM);
        unsigned short* Wb       = (unsigned short*)(ws + SZ_ENCB + SZ_SM + SZ_PBI);

        const int encBlocks = B_ * L_ * D_ / 4096;   // 4096
        const int nBlocks   = encBlocks + 256 + B_ + B_ * D_ / 64;  // 4420
        hipLaunchKernelGGL(prep_all_kernel, dim3(nBlocks), dim3(512), 0, stream,
                           enc, W, probs, ct, bidx, encb, Wb, pbi, smoothed, encBlocks);
        hipLaunchKernelGGL(gemm8_kernel, dim3(256), dim3(512), 0, stream,
                           encb, Wb, smoothed, pbi, out);
    } else {
        float*          smoothed = (float*)ws;
        int*            pbi      = (int*)(ws + SZ_SM);
        unsigned short* Wb       = (unsigned short*)(ws + SZ_SM + SZ_PBI);
        const int nBlocks = 0 + 256 + B_ + B_ * D_ / 64;
        hipLaunchKernelGGL(prep_all_kernel, dim3(nBlocks), dim3(512), 0, stream,
                           enc, W, probs, ct, bidx, (unsigned short*)ws /*unused*/, Wb, pbi, smoothed, 0);
        hipLaunchKernelGGL(gemm_fused_kernel, dim3(B_ * L_ / 128, D_ / 128), dim3(256), 0, stream,
                           enc, Wb, smoothed, pbi, out);
    }
}

// Round 8
// 171.817 us; speedup vs baseline: 1.0168x; 1.0082x over previous
//
#include <hip/hip_runtime.h>
#include <hip/hip_bf16.h>
#include <stdint.h>

// B=4, L=4096, D=1024, M_MAX=512
// out[b,l,e] = smoothed[b, pbi[b,l], e] + sum_d enc[b,l,d] * W[e,d]

#define B_  4
#define L_  4096
#define D_  1024
#define M_  512

typedef __attribute__((ext_vector_type(8))) short bf16x8;
typedef __attribute__((ext_vector_type(4))) float f32x4;
typedef __attribute__((ext_vector_type(8))) unsigned short u16x8;

__device__ inline unsigned short f2bf(float f) {
    unsigned u = __float_as_uint(f);
    u += 0x7fffu + ((u >> 16) & 1u);   // RNE
    return (unsigned short)(u >> 16);
}

// ============ prep_all: enc cvt + W cvt + pbi + EMA in ONE launch (unchanged control) ============
__global__ void prep_all_kernel(const float* __restrict__ enc, const float* __restrict__ W,
                                const float* __restrict__ probs, const float* __restrict__ ct,
                                const int* __restrict__ bidx,
                                unsigned short* __restrict__ encb, unsigned short* __restrict__ Wb,
                                int* __restrict__ pbi, float* __restrict__ smoothed,
                                int encBlocks) {
    __shared__ int part[512];
    __shared__ float ad[M_], bdp[M_];
    __shared__ float Ac[8][64], Bc[8][64], Hin[8][64];

    const int blk = blockIdx.x;
    const int t   = threadIdx.x;

    if (blk < encBlocks + 256) {
        const float* src; unsigned short* dst; size_t i;
        if (blk < encBlocks) { src = enc; dst = encb; i = (size_t)blk * 512 + t; }
        else                 { src = W;   dst = Wb;   i = (size_t)(blk - encBlocks) * 512 + t; }
        float4 x0 = ((const float4*)src)[2 * i];
        float4 x1 = ((const float4*)src)[2 * i + 1];
        u16x8 v;
        v[0] = f2bf(x0.x); v[1] = f2bf(x0.y); v[2] = f2bf(x0.z); v[3] = f2bf(x0.w);
        v[4] = f2bf(x1.x); v[5] = f2bf(x1.y); v[6] = f2bf(x1.z); v[7] = f2bf(x1.w);
        ((u16x8*)dst)[i] = v;
    } else if (blk < encBlocks + 260) {
        int b = blk - (encBlocks + 256);
        const float4* pr = (const float4*)(probs + b * L_);
        int cnt[8]; int s = 0;
        #pragma unroll
        for (int u = 0; u < 2; ++u) {
            float4 x = pr[t * 2 + u];
            s += (x.x >= 0.5f); cnt[u * 4 + 0] = s;
            s += (x.y >= 0.5f); cnt[u * 4 + 1] = s;
            s += (x.z >= 0.5f); cnt[u * 4 + 2] = s;
            s += (x.w >= 0.5f); cnt[u * 4 + 3] = s;
        }
        part[t] = s;
        __syncthreads();
        for (int off = 1; off < 512; off <<= 1) {
            int x = part[t];
            int y = (t >= off) ? part[t - off] : 0;
            __syncthreads();
            part[t] = x + y;
            __syncthreads();
        }
        int excl = part[t] - s;
        int4* po = (int4*)(pbi + b * L_ + t * 8);
        #pragma unroll
        for (int u = 0; u < 2; ++u) {
            int4 o;
            o.x = max(excl + cnt[u * 4 + 0] - 1, 0);
            o.y = max(excl + cnt[u * 4 + 1] - 1, 0);
            o.z = max(excl + cnt[u * 4 + 2] - 1, 0);
            o.w = max(excl + cnt[u * 4 + 3] - 1, 0);
            po[u] = o;
        }
    } else {
        int idx = blk - (encBlocks + 260);
        int b  = idx >> 4;
        int d0 = (idx & 15) * 64;
        int dl = t & 63;
        int ch = t >> 6;
        {
            int m = t;
            int bi = bidx[b * M_ + m];
            float p = fmaxf(probs[b * L_ + bi], 0.1f);
            ad[m]  = (m == 0) ? 0.0f : fmaxf(1.0f - p, 1e-7f);
            bdp[m] = (m == 0) ? 1.0f : p;
        }
        __syncthreads();
        const float* ctp = ct + ((size_t)b * M_ + ch * 64) * D_ + d0 + dl;
        float A = 1.0f, Bv = 0.0f;
        #pragma unroll 8
        for (int i = 0; i < 64; ++i) {
            int m = ch * 64 + i;
            float c = ctp[(size_t)i * D_];
            A  = ad[m] * A;
            Bv = ad[m] * Bv + bdp[m] * c;
        }
        Ac[ch][dl] = A; Bc[ch][dl] = Bv;
        __syncthreads();
        if (t < 64) {
            float H = 0.0f;
            #pragma unroll
            for (int c = 0; c < 8; ++c) {
                Hin[c][t] = H;
                H = Ac[c][t] * H + Bc[c][t];
            }
        }
        __syncthreads();
        float h = Hin[ch][dl];
        float* smp = smoothed + ((size_t)b * M_ + ch * 64) * D_ + d0 + dl;
        #pragma unroll 8
        for (int i = 0; i < 64; ++i) {
            int m = ch * 64 + i;
            float c = ctp[(size_t)i * D_];
            h = ad[m] * h + bdp[m] * c;
            smp[(size_t)i * D_] = h;
        }
    }
}

// ============ GEMM: 256x256, BK=64, 8-phase counted-vmcnt schedule ============
// 512 thr = 8 waves (2M x 4N); per-wave 128x64 out = 8x4 16x16 frags.
// LDS 128 KiB: A[db][half] 128x64 bf16 (16KiB each) at (db*2+h)*16384;
//              B[db][half] at 65536 + (db*2+h)*16384.
// Swizzle (R7 FIX): col_byte ^= (row&7)<<4  -- 3-bit XOR spreads every
// ds_read_b128's 64 lanes over all 8 16B col-slots (8 lanes/slot = 8-cy min).
// Rows are 128B (= 32 banks) so only col_byte selects banks; the old bit5-only
// XOR spanned half the banks -> structural 2x conflict (measured 3.1M).
// Source pre-swizzled for global_load_lds (linear dest), rule #21.
#define NTT 16   // K tiles (K=1024 / BK=64)

__global__ __launch_bounds__(512, 2) void gemm8_kernel(
    const unsigned short* __restrict__ encb, const unsigned short* __restrict__ Wb,
    const float* __restrict__ smoothed, const int* __restrict__ pbi,
    float* __restrict__ out)
{
    __shared__ __align__(16) char smem[131072];

    const int tid  = threadIdx.x;
    const int lane = tid & 63;
    const int w    = tid >> 6;        // 0..7
    const int wm   = w >> 2;          // 0..1
    const int wn   = w & 3;           // 0..3
    const int l15  = lane & 15;
    const int l16  = lane >> 4;

    // bijective XCD swizzle: 256 blocks over 8 XCDs; each XCD gets 8 row-tiles x 4 col-tiles
    const int orig = blockIdx.x;
    const int rm   = (orig & 7) * 32 + (orig >> 3);
    const size_t rowBase = (size_t)(rm >> 2) * 256;
    const int    colBase = (rm & 3) * 256;

    // R7: full 3-bit read swizzle; row&7 == l15&7 for every fragment row (frag base is mult of 16)
    const int rsw   = (l15 & 7) << 4;
    const int colb0 = (0  + l16 * 16) ^ rsw;
    const int colb1 = (64 + l16 * 16) ^ rsw;

    // per-dbuf read bases (byte offsets into smem)
    const int aRd0 = (0 + wm) * 16384 + l15 * 128;
    const int aRd1 = (2 + wm) * 16384 + l15 * 128;
    const int bRd0 = 65536 + (0 + (wn >> 1)) * 16384 + ((wn & 1) * 64 + l15) * 128;
    const int bRd1 = 65536 + (2 + (wn >> 1)) * 16384 + ((wn & 1) * 64 + l15) * 128;

    // staging: thread handles rows {srow, 64+srow} (same mod 8), 16B slot pre-swizzled
    const int srow  = tid >> 3;                        // 0..63
    const int sslot = (tid & 7) ^ ((tid >> 3) & 7);    // (col slot) ^ (row&7)
    const unsigned short* aSrc = encb + (rowBase + srow) * D_ + sslot * 8;
    const unsigned short* bSrc = Wb + ((size_t)colBase + srow) * D_ + sslot * 8;

#define STAGE_A(T, db, h)                                                                 \
  { _Pragma("unroll") for (int i_ = 0; i_ < 2; ++i_) {                                    \
      const unsigned short* g_ = aSrc + (size_t)((h) * 128 + i_ * 64) * D_ + (T) * 64;    \
      __builtin_amdgcn_global_load_lds(                                                   \
          (const __attribute__((address_space(1))) void*)g_,                              \
          (__attribute__((address_space(3))) void*)(smem + ((db)*2+(h))*16384 + i_*8192 + tid*16), \
          16, 0, 0); } }

#define STAGE_B(T, db, h)                                                                 \
  { _Pragma("unroll") for (int i_ = 0; i_ < 2; ++i_) {                                    \
      const unsigned short* g_ = bSrc + (size_t)((h) * 128 + i_ * 64) * D_ + (T) * 64;    \
      __builtin_amdgcn_global_load_lds(                                                   \
          (const __attribute__((address_space(1))) void*)g_,                              \
          (__attribute__((address_space(3))) void*)(smem + 65536 + ((db)*2+(h))*16384 + i_*8192 + tid*16), \
          16, 0, 0); } }

#define LDSA(aRd, mbase)                                                                  \
  { _Pragma("unroll") for (int m_ = 0; m_ < 4; ++m_) {                                    \
      a[m_*2+0] = *(const bf16x8*)(smem + (aRd) + ((mbase)+m_)*2048 + colb0);             \
      a[m_*2+1] = *(const bf16x8*)(smem + (aRd) + ((mbase)+m_)*2048 + colb1); } }

#define LDSB(bRd, nbase)                                                                  \
  { _Pragma("unroll") for (int n_ = 0; n_ < 2; ++n_) {                                    \
      b[((nbase)+n_)*2+0] = *(const bf16x8*)(smem + (bRd) + ((nbase)+n_)*2048 + colb0);   \
      b[((nbase)+n_)*2+1] = *(const bf16x8*)(smem + (bRd) + ((nbase)+n_)*2048 + colb1); } }

#define MFMA_Q(mbase, nbase)                                                              \
  { _Pragma("unroll") for (int m_ = 0; m_ < 4; ++m_)                                      \
    _Pragma("unroll") for (int n_ = 0; n_ < 2; ++n_) {                                    \
      acc[(mbase)+m_][(nbase)+n_] = __builtin_amdgcn_mfma_f32_16x16x32_bf16(              \
          a[m_*2+0], b[((nbase)+n_)*2+0], acc[(mbase)+m_][(nbase)+n_], 0, 0, 0);          \
      acc[(mbase)+m_][(nbase)+n_] = __builtin_amdgcn_mfma_f32_16x16x32_bf16(              \
          a[m_*2+1], b[((nbase)+n_)*2+1], acc[(mbase)+m_][(nbase)+n_], 0, 0, 0); } }

#define PH_OPEN()  do { __builtin_amdgcn_sched_barrier(0); __builtin_amdgcn_s_barrier();  \
    __builtin_amdgcn_sched_barrier(0);                                                    \
    asm volatile("s_waitcnt lgkmcnt(0)" ::: "memory");                                    \
    __builtin_amdgcn_sched_barrier(0); __builtin_amdgcn_s_setprio(1); } while (0)

#define PH_CLOSE() do { __builtin_amdgcn_s_setprio(0); __builtin_amdgcn_sched_barrier(0); \
    __builtin_amdgcn_s_barrier(); __builtin_amdgcn_sched_barrier(0); } while (0)

    f32x4 acc[8][4] = {};
    bf16x8 a[8], b[8];

    // ---- prologue: T0 full + T1 B-halves (12 loads/thr); confirm T0 (allow T1-B outstanding) ----
    STAGE_A(0, 0, 0); STAGE_A(0, 0, 1);
    STAGE_B(0, 0, 0); STAGE_B(0, 0, 1);
    STAGE_B(1, 1, 0); STAGE_B(1, 1, 1);
    asm volatile("s_waitcnt vmcnt(4)" ::: "memory");
    __builtin_amdgcn_s_barrier();
    __builtin_amdgcn_sched_barrier(0);

    #pragma unroll 1
    for (int i = 0; i < NTT / 2; ++i) {
        const int t1 = 2 * i + 1;
        const int t2 = (2 * i + 2 < NTT) ? 2 * i + 2 : NTT - 1;
        const int t3 = (2 * i + 3 < NTT) ? 2 * i + 3 : NTT - 1;
        // ph1
        LDSA(aRd0, 0); LDSB(bRd0, 0);
        STAGE_A(t1, 1, 0);
        PH_OPEN(); MFMA_Q(0, 0); PH_CLOSE();
        // ph2
        LDSB(bRd0, 2);
        STAGE_A(t1, 1, 1);
        PH_OPEN(); MFMA_Q(0, 2); PH_CLOSE();
        // ph3
        LDSA(aRd0, 4);
        STAGE_B(t2, 0, 0);
        PH_OPEN(); MFMA_Q(4, 0); PH_CLOSE();
        // ph4
        STAGE_B(t2, 0, 1);
        asm volatile("s_waitcnt vmcnt(4)" ::: "memory");
        PH_OPEN(); MFMA_Q(4, 2); PH_CLOSE();
        // ph5
        LDSA(aRd1, 0); LDSB(bRd1, 0);
        STAGE_A(t2, 0, 0);
        PH_OPEN(); MFMA_Q(0, 0); PH_CLOSE();
        // ph6
        LDSB(bRd1, 2);
        STAGE_A(t2, 0, 1);
        PH_OPEN(); MFMA_Q(0, 2); PH_CLOSE();
        // ph7
        LDSA(aRd1, 4);
        STAGE_B(t3, 1, 0);
        PH_OPEN(); MFMA_Q(4, 0); PH_CLOSE();
        // ph8
        STAGE_B(t3, 1, 1);
        asm volatile("s_waitcnt vmcnt(4)" ::: "memory");
        PH_OPEN(); MFMA_Q(4, 2); PH_CLOSE();
    }
#undef STAGE_A
#undef STAGE_B
#undef LDSA
#undef LDSB
#undef MFMA_Q
#undef PH_OPEN
#undef PH_CLOSE

    // ---- epilogue: fused plugback gather + add, fp32 store ----
    #pragma unroll
    for (int m = 0; m < 8; ++m) {
        const size_t row0 = rowBase + wm * 128 + m * 16;
        #pragma unroll
        for (int j = 0; j < 4; ++j) {
            size_t row = row0 + l16 * 4 + j;
            int bb2 = (int)(row >> 12);
            int pb  = pbi[row];
            pb = pb < (M_ - 1) ? pb : (M_ - 1);
            const float* sm = smoothed + ((size_t)(bb2 * M_ + pb)) * D_;
            #pragma unroll
            for (int n = 0; n < 4; ++n) {
                int col = colBase + wn * 64 + n * 16 + l15;
                out[row * D_ + col] = acc[m][n][j] + sm[col];
            }
        }
    }
}

// ---------------- fallback fused-convert GEMM (if ws too small; unlikely path) ----------------
#define LDP 72
__global__ __launch_bounds__(256, 2) void gemm_fused_kernel(
    const float* __restrict__ enc, const unsigned short* __restrict__ Wb,
    const float* __restrict__ smoothed, const int* __restrict__ pbi,
    float* __restrict__ out)
{
    __shared__ unsigned short Asf[128][LDP];
    __shared__ unsigned short Bsf[128][LDP];
    const int tid  = threadIdx.x;
    const int lane = tid & 63;
    const int wid  = tid >> 6;
    const int wm   = wid >> 1;
    const int wn   = wid & 1;
    const int l15  = lane & 15;
    const int l16  = lane >> 4;
    const size_t rowBase = (size_t)blockIdx.x * 128;
    const int    colBase = blockIdx.y * 128;
    f32x4 acc[4][4] = {};
    for (int t = 0; t < D_ / 64; ++t) {
        const int k0 = t * 64;
        #pragma unroll
        for (int i = 0; i < 4; ++i) {
            int c = i * 256 + tid;
            int r = c >> 3;
            int c8 = c & 7;
            const float4* g = (const float4*)(enc + (rowBase + r) * D_ + k0 + c8 * 8);
            float4 x0 = g[0];
            float4 x1 = g[1];
            u16x8 v;
            v[0] = f2bf(x0.x); v[1] = f2bf(x0.y); v[2] = f2bf(x0.z); v[3] = f2bf(x0.w);
            v[4] = f2bf(x1.x); v[5] = f2bf(x1.y); v[6] = f2bf(x1.z); v[7] = f2bf(x1.w);
            *(u16x8*)&Asf[r][c8 * 8] = v;
        }
        #pragma unroll
        for (int i = 0; i < 4; ++i) {
            int c = i * 256 + tid;
            int r = c >> 3;
            int c8 = c & 7;
            u16x8 v = *(const u16x8*)(Wb + (size_t)(colBase + r) * D_ + k0 + c8 * 8);
            *(u16x8*)&Bsf[r][c8 * 8] = v;
        }
        __syncthreads();
        #pragma unroll
        for (int kk = 0; kk < 2; ++kk) {
            bf16x8 a[4], bbf[4];
            #pragma unroll
            for (int m = 0; m < 4; ++m)
                a[m] = *(const bf16x8*)&Asf[wm * 64 + m * 16 + l15][kk * 32 + l16 * 8];
            #pragma unroll
            for (int n = 0; n < 4; ++n)
                bbf[n] = *(const bf16x8*)&Bsf[wn * 64 + n * 16 + l15][kk * 32 + l16 * 8];
            #pragma unroll
            for (int m = 0; m < 4; ++m)
                #pragma unroll
                for (int n = 0; n < 4; ++n)
                    acc[m][n] = __builtin_amdgcn_mfma_f32_16x16x32_bf16(a[m], bbf[n], acc[m][n], 0, 0, 0);
        }
        __syncthreads();
    }
    #pragma unroll
    for (int m = 0; m < 4; ++m) {
        #pragma unroll
        for (int j = 0; j < 4; ++j) {
            size_t row = rowBase + wm * 64 + m * 16 + l16 * 4 + j;
            int b  = (int)(row >> 12);
            int pb = pbi[row];
            pb = pb < (M_ - 1) ? pb : (M_ - 1);
            const float* sm = smoothed + ((size_t)(b * M_ + pb)) * D_;
            #pragma unroll
            for (int n = 0; n < 4; ++n) {
                int col = colBase + wn * 64 + n * 16 + l15;
                out[row * D_ + col] = acc[m][n][j] + sm[col];
            }
        }
    }
}

extern "C" void kernel_launch(void* const* d_in, const int* in_sizes, int n_in,
                              void* d_out, int out_size, void* d_ws, size_t ws_size,
                              hipStream_t stream) {
    const float* ct    = (const float*)d_in[0];
    const float* enc   = (const float*)d_in[1];
    const float* probs = (const float*)d_in[2];
    const int*   bidx  = (const int*)d_in[3];
    const float* W     = (const float*)d_in[5];
    float* out = (float*)d_out;
    char*  ws  = (char*)d_ws;

    const size_t SZ_ENCB = (size_t)B_ * L_ * D_ * 2;   // 32 MiB
    const size_t SZ_SM   = (size_t)B_ * M_ * D_ * 4;   // 8 MiB
    const size_t SZ_PBI  = (size_t)B_ * L_ * 4;        // 64 KiB
    const size_t SZ_WB   = (size_t)D_ * D_ * 2;        // 2 MiB

    if (ws_size >= SZ_ENCB + SZ_SM + SZ_PBI + SZ_WB) {
        unsigned short* encb     = (unsigned short*)ws;
        float*          smoothed = (float*)(ws + SZ_ENCB);
        int*            pbi      = (int*)(ws + SZ_ENCB + SZ_SM);
        unsigned short* Wb       = (unsigned short*)(ws + SZ_ENCB + SZ_SM + SZ_PBI);

        const int encBlocks = B_ * L_ * D_ / 4096;   // 4096
        const int nBlocks   = encBlocks + 256 + B_ + B_ * D_ / 64;  // 4420
        hipLaunchKernelGGL(prep_all_kernel, dim3(nBlocks), dim3(512), 0, stream,
                           enc, W, probs, ct, bidx, encb, Wb, pbi, smoothed, encBlocks);
        hipLaunchKernelGGL(gemm8_kernel, dim3(256), dim3(512), 0, stream,
                           encb, Wb, smoothed, pbi, out);
    } else {
        float*          smoothed = (float*)ws;
        int*            pbi      = (int*)(ws + SZ_SM);
        unsigned short* Wb       = (unsigned short*)(ws + SZ_SM + SZ_PBI);
        const int nBlocks = 0 + 256 + B_ + B_ * D_ / 64;
        hipLaunchKernelGGL(prep_all_kernel, dim3(nBlocks), dim3(512), 0, stream,
                           enc, W, probs, ct, bidx, (unsigned short*)ws /*unused*/, Wb, pbi, smoothed, 0);
        hipLaunchKernelGGL(gemm_fused_kernel, dim3(B_ * L_ / 128, D_ / 128), dim3(256), 0, stream,
                           enc, Wb, smoothed, pbi, out);
    }
}